// Round 8
// baseline (303.539 us; speedup 1.0000x reference)
//
#include <hip/hip_runtime.h>
#include <hip/hip_bf16.h>
#include <math.h>

// ---------------------------------------------------------------------------
// PSI_47931835024047: x@W_omega -> chunked phase cumsum/rotation -> LN ->
//                     W1+gelu -> W2 + residual.
// B=4 S=4096 D=512 C=64. All GEMMs bf16 MFMA.
// R8: BK=32 double-buffer (32 KB LDS) -> register-limited 3 blocks/CU
//     (R7's BK=64 dbuf = 64 KB capped at 2 blocks/CU; slot 3675 cyc vs
//     LDS-pipe 2000 = ~1700 cyc exposed latency from too few waves).
//     3 resident blocks stagger barriers; prefetch still ages one full
//     compute phase. LDS swizzle: R4's proven BK=32 map c^((r>>1)&3).
//     Carried: one barrier/iter dbuf, XCD tile swizzle, omega bf16,
//     bf16 scan inputs.
// ---------------------------------------------------------------------------

typedef __bf16 bf16x8 __attribute__((ext_vector_type(8)));
typedef __bf16 bf16x4 __attribute__((ext_vector_type(4)));
typedef __bf16 bf16x2 __attribute__((ext_vector_type(2)));
typedef float  f32x4  __attribute__((ext_vector_type(4)));

typedef __attribute__((address_space(1))) void* gas_ptr;
typedef __attribute__((address_space(3))) void* las_ptr;

// wave-uniform LDS base; each lane deposits 16 B at base + lane*16
__device__ __forceinline__ void load_lds16(const void* g, void* l) {
    __builtin_amdgcn_global_load_lds((gas_ptr)g, (las_ptr)l, 16, 0, 0);
}

// ---------------------------------------------------------------------------
// Elementwise fp32 -> bf16 cast (vectorized x4)
// ---------------------------------------------------------------------------
__global__ void cast_kernel(const float* __restrict__ in, __bf16* __restrict__ out, int n4)
{
    int i = blockIdx.x * blockDim.x + threadIdx.x;
    if (i < n4) {
        float4 v = ((const float4*)in)[i];
        bf16x4 o = { (__bf16)v.x, (__bf16)v.y, (__bf16)v.z, (__bf16)v.w };
        ((bf16x4*)out)[i] = o;
    }
}

// ---------------------------------------------------------------------------
// Transpose + cast: in (K x N) fp32 row-major -> out (N x K) bf16 row-major.
// ---------------------------------------------------------------------------
__global__ void transpose_cast_kernel(const float* __restrict__ in, __bf16* __restrict__ out,
                                      int K, int N)
{
    __shared__ float tile[32][33];
    int n0 = blockIdx.x * 32, k0 = blockIdx.y * 32;
    int tx = threadIdx.x, ty = threadIdx.y;
    #pragma unroll
    for (int i = 0; i < 32; i += 8)
        tile[ty + i][tx] = in[(size_t)(k0 + ty + i) * N + n0 + tx];
    __syncthreads();
    #pragma unroll
    for (int i = 0; i < 32; i += 8)
        out[(size_t)(n0 + ty + i) * K + k0 + tx] = (__bf16)tile[tx][ty + i];
}

// ---------------------------------------------------------------------------
// bf16 MFMA GEMM: C[m][n] = sum_k A[m][k] * Bt[n][k].
// 128x128 block tile, 4 waves each 64x64 (4x4 of 16x16x32 MFMA), BK=32.
// DOUBLE-BUFFERED LDS (2 x 8 KB per operand = 32 KB): one barrier per
// K-iter; prefetch of tile i+1 issued right after the barrier so the
// vmcnt(0) drain at the NEXT barrier covers loads aged a full MFMA phase.
//
// LDS rows: 64 B (32 elems), chunk c of row r at position c ^ ((r>>1)&3).
//   Staging: lane l -> row (l>>2), global chunk (l&3)^((l>>3)&3); 4-lane
//   group = one permuted 64-B segment (coalesced). Wave stages rows
//   [w*32, w*32+32) per operand in 2 calls of 16 rows.
//   Fragment read: lane l reads row +i*16+(l&15), chunk (l>>4)^(((l&15)>>1)&3):
//   2 lanes per bank-quad per 16-lane group -> conflict-free (m136: 2-way free).
// Tile swizzle: xcd = bid&7; same-XCD blocks share tile_m -> A-strip L2 hit.
//
// MODE 0: +bias, store bf16            (omega)
// MODE 1: +bias, exact gelu, store bf16 (h)
// MODE 2: +bias, +resid fp32, store fp32 (final out)
// ---------------------------------------------------------------------------
template<int MODE>
__global__ __launch_bounds__(256)
void gemm_kernel(const __bf16* __restrict__ A, const __bf16* __restrict__ Bt,
                 const float* __restrict__ bias, const float* __restrict__ resid,
                 void* __restrict__ out, int M, int N, int K)
{
    __shared__ __bf16 As[2][128 * 32];
    __shared__ __bf16 Bs[2][128 * 32];

    const int tid     = threadIdx.x;
    const int tiles_n = N >> 7;                 // 4 or 8 (power of 2)
    const int ln_tn   = __ffs(tiles_n) - 1;
    const int per_m   = (M >> 7) >> 3;          // 128-row tiles per XCD

    const int xcd = blockIdx.x & 7;
    const int j   = blockIdx.x >> 3;
    const int tile_m = (xcd * per_m + (j >> ln_tn)) << 7;
    const int tile_n = (j & (tiles_n - 1)) << 7;

    const int wave = tid >> 6;
    const int lane = tid & 63;

    // staging map: lane l -> row (l>>2), chunk (l&3)^((l>>3)&3)
    const int srow = lane >> 2;                             // 0..15
    const int scol = ((lane & 3) ^ ((lane >> 3) & 3)) << 3; // elem offset

    const __bf16* Ag0 = A  + (size_t)(tile_m + wave * 32 +      srow) * K + scol;
    const __bf16* Ag1 = A  + (size_t)(tile_m + wave * 32 + 16 + srow) * K + scol;
    const __bf16* Bg0 = Bt + (size_t)(tile_n + wave * 32 +      srow) * K + scol;
    const __bf16* Bg1 = Bt + (size_t)(tile_n + wave * 32 + 16 + srow) * K + scol;

    const int m0 = (wave >> 1) << 6;
    const int n0 = (wave & 1) << 6;
    const int lr = lane & 15;
    const int q  = lane >> 4;
    // swizzled fragment chunk (elem offset): (q ^ ((lr>>1)&3))*8
    const int fswz = (q ^ ((lr >> 1) & 3)) << 3;

    f32x4 acc[4][4];
    #pragma unroll
    for (int i = 0; i < 4; ++i)
        #pragma unroll
        for (int jj = 0; jj < 4; ++jj)
            acc[i][jj] = (f32x4){0.f, 0.f, 0.f, 0.f};

    const int nIter = K >> 5;

    // prologue: stage tile 0 into buffer 0
    load_lds16(Ag0, &As[0][(wave * 32)      * 32]);
    load_lds16(Ag1, &As[0][(wave * 32 + 16) * 32]);
    load_lds16(Bg0, &Bs[0][(wave * 32)      * 32]);
    load_lds16(Bg1, &Bs[0][(wave * 32 + 16) * 32]);

    for (int it = 0; it < nIter; ++it) {
        const int cur = it & 1;
        __syncthreads();   // drains prefetch issued last iter (aged thru MFMA)
        if (it + 1 < nIter) {
            const int nk = (it + 1) << 5;
            load_lds16(Ag0 + nk, &As[cur ^ 1][(wave * 32)      * 32]);
            load_lds16(Ag1 + nk, &As[cur ^ 1][(wave * 32 + 16) * 32]);
            load_lds16(Bg0 + nk, &Bs[cur ^ 1][(wave * 32)      * 32]);
            load_lds16(Bg1 + nk, &Bs[cur ^ 1][(wave * 32 + 16) * 32]);
        }

        const __bf16* as = As[cur];
        const __bf16* bs = Bs[cur];
        bf16x8 af[4], bq[4];
        #pragma unroll
        for (int i = 0; i < 4; ++i)
            af[i] = *(const bf16x8*)&as[(m0 + i * 16 + lr) * 32 + fswz];
        #pragma unroll
        for (int jj = 0; jj < 4; ++jj)
            bq[jj] = *(const bf16x8*)&bs[(n0 + jj * 16 + lr) * 32 + fswz];
        #pragma unroll
        for (int i = 0; i < 4; ++i)
            #pragma unroll
            for (int jj = 0; jj < 4; ++jj)
                acc[i][jj] = __builtin_amdgcn_mfma_f32_16x16x32_bf16(af[i], bq[jj], acc[i][jj], 0, 0, 0);
    }

    // epilogue — C/D layout: col = lane&15, row = (lane>>4)*4 + reg  [m89/m91]
    const int orow0 = tile_m + m0 + (q << 2);
    const int ocol0 = tile_n + n0 + lr;
    #pragma unroll
    for (int i = 0; i < 4; ++i) {
        #pragma unroll
        for (int jj = 0; jj < 4; ++jj) {
            const int col = ocol0 + jj * 16;
            const float bv = bias[col];
            #pragma unroll
            for (int r = 0; r < 4; ++r) {
                const int row = orow0 + i * 16 + r;
                float v = acc[i][jj][r] + bv;
                size_t idx = (size_t)row * N + col;
                if (MODE == 0) {
                    ((__bf16*)out)[idx] = (__bf16)v;
                } else if (MODE == 1) {
                    float g = 0.5f * v * (1.0f + erff(v * 0.70710678118654752f));
                    ((__bf16*)out)[idx] = (__bf16)g;
                } else {
                    ((float*)out)[idx] = v + resid[idx];
                }
            }
        }
    }
}

// ---------------------------------------------------------------------------
// Per-chunk phase cumsum + rotation + running means + LayerNorm.
// One block per (b, chunk): 512 threads (8 waves), one d per thread; bf16
// inputs (xb, omega), f32 math. Double-buffered reduction slots, prefetch.
// ---------------------------------------------------------------------------
__global__ __launch_bounds__(512)
void scan_ln_kernel(const __bf16* __restrict__ xb, const __bf16* __restrict__ omega,
                    const float* __restrict__ log_scale,
                    const float* __restrict__ gamma, const float* __restrict__ beta,
                    __bf16* __restrict__ ctx)
{
    const int chunk = blockIdx.x;        // 0..255  (b*64 + n)
    const int d     = threadIdx.x;       // 0..511
    const int lane  = d & 63, wv = d >> 6;   // 8 waves
    const size_t base = (size_t)chunk * 64 * 512;

    const float scale = expf(log_scale[d]);
    const float g0 = gamma[d], g1 = gamma[512 + d], g2 = gamma[1024 + d], g3 = gamma[1536 + d];
    const float e0 = beta[d],  e1 = beta[512 + d],  e2 = beta[1024 + d],  e3 = beta[1536 + d];

    float phi = 0.f, scr = 0.f, sci = 0.f;
    __shared__ float red[2][16];         // [slot][8 sums | 8 sumsq]

    float om_n = (float)omega[base + d];
    float xv_n = (float)xb[base + d];

    for (int c = 0; c < 64; ++c) {
        const float om = om_n;
        const float xv = xv_n;
        if (c < 63) {
            om_n = (float)omega[base + (size_t)(c + 1) * 512 + d];
            xv_n = (float)xb[base + (size_t)(c + 1) * 512 + d];
        }
        phi += om * scale * rsqrtf((float)(c + 1));
        float sp, cp;
        __sincosf(phi, &sp, &cp);
        const float cr = xv * cp, ci = xv * sp;
        scr += cr; sci += ci;
        const float inv = 1.0f / (float)(c + 1);
        const float mr = scr * inv, mi = sci * inv;
        const float rr = mr * cp + mi * sp;
        const float ri = mi * cp - mr * sp;

        float s  = cr + ci + rr + ri;
        float s2 = cr * cr + ci * ci + rr * rr + ri * ri;
        #pragma unroll
        for (int o = 32; o > 0; o >>= 1) {
            s  += __shfl_down(s, o);
            s2 += __shfl_down(s2, o);
        }
        if (lane == 0) { red[c & 1][wv] = s; red[c & 1][8 + wv] = s2; }
        __syncthreads();
        float S = 0.f, S2 = 0.f;
        #pragma unroll
        for (int i = 0; i < 8; ++i) { S += red[c & 1][i]; S2 += red[c & 1][8 + i]; }
        const float mu   = S * (1.0f / 2048.0f);
        const float var  = S2 * (1.0f / 2048.0f) - mu * mu;
        const float rstd = rsqrtf(var + 1e-5f);

        const size_t ob = ((size_t)chunk * 64 + c) * 2048;
        ctx[ob + d]        = (__bf16)(((cr - mu) * rstd) * g0 + e0);
        ctx[ob + 512 + d]  = (__bf16)(((ci - mu) * rstd) * g1 + e1);
        ctx[ob + 1024 + d] = (__bf16)(((rr - mu) * rstd) * g2 + e2);
        ctx[ob + 1536 + d] = (__bf16)(((ri - mu) * rstd) * g3 + e3);
    }
}

// ---------------------------------------------------------------------------
// Workspace layout (bytes):
//   xb    @ 0          : 16,777,216  (16384x512 bf16)
//   womT  @ 16777216   : 524,288     (512x512 bf16, transposed)
//   w1T   @ 17301504   : 4,194,304   (1024x2048 bf16, transposed)
//   w2T   @ 21495808   : 1,048,576   (512x1024 bf16, transposed)
//   omega @ 22544384   : 16,777,216  (16384x512 bf16) — region reused as h
//   h     @ 22544384   : 33,554,432  (16384x1024 bf16)
//   ctx   @ 56098816   : 67,108,864  (16384x2048 bf16)
// ---------------------------------------------------------------------------
extern "C" void kernel_launch(void* const* d_in, const int* in_sizes, int n_in,
                              void* d_out, int out_size, void* d_ws, size_t ws_size,
                              hipStream_t stream)
{
    const float* x         = (const float*)d_in[0];
    const float* W_omega   = (const float*)d_in[1];
    const float* b_omega   = (const float*)d_in[2];
    const float* log_scale = (const float*)d_in[3];
    const float* ln_gamma  = (const float*)d_in[4];
    const float* ln_beta   = (const float*)d_in[5];
    const float* W1        = (const float*)d_in[6];
    const float* b1        = (const float*)d_in[7];
    const float* W2        = (const float*)d_in[8];
    const float* b2        = (const float*)d_in[9];
    float* out = (float*)d_out;

    char* ws = (char*)d_ws;
    __bf16* xb    = (__bf16*)(ws);
    __bf16* womT  = (__bf16*)(ws + 16777216);
    __bf16* w1T   = (__bf16*)(ws + 17301504);
    __bf16* w2T   = (__bf16*)(ws + 21495808);
    __bf16* omega = (__bf16*)(ws + 22544384);
    __bf16* hbuf  = (__bf16*)(ws + 22544384);   // reuses omega region
    __bf16* ctx   = (__bf16*)(ws + 56098816);

    // 1. casts / weight transposes
    cast_kernel<<<8192, 256, 0, stream>>>(x, xb, 2097152);
    transpose_cast_kernel<<<dim3(16, 16), dim3(32, 8), 0, stream>>>(W_omega, womT, 512, 512);
    transpose_cast_kernel<<<dim3(32, 64), dim3(32, 8), 0, stream>>>(W1,      w1T,  2048, 1024);
    transpose_cast_kernel<<<dim3(16, 32), dim3(32, 8), 0, stream>>>(W2,      w2T,  1024, 512);

    // 2. omega = x @ W_omega + b_omega   (bf16 out)
    gemm_kernel<0><<<512, 256, 0, stream>>>(xb, womT, b_omega, nullptr, omega, 16384, 512, 512);

    // 3. chunk scan + LayerNorm -> ctx (bf16, 16384x2048)
    scan_ln_kernel<<<256, 512, 0, stream>>>(xb, omega, log_scale, ln_gamma, ln_beta, ctx);

    // 4. h = gelu(ctx @ W1 + b1)  (bf16 out)
    gemm_kernel<1><<<1024, 256, 0, stream>>>(ctx, w1T, b1, nullptr, hbuf, 16384, 1024, 2048);

    // 5. out = x + h @ W2 + b2    (fp32 out)
    gemm_kernel<2><<<512, 256, 0, stream>>>(hbuf, w2T, b2, x, out, 16384, 512, 1024);
}

// Round 9
// 271.073 us; speedup vs baseline: 1.1198x; 1.1198x over previous
//
#include <hip/hip_runtime.h>
#include <hip/hip_bf16.h>
#include <math.h>

// ---------------------------------------------------------------------------
// PSI_47931835024047: x@W_omega -> chunked phase cumsum/rotation -> LN ->
//                     W1+gelu -> W2 + residual.
// B=4 S=4096 D=512 C=64. All GEMMs bf16 MFMA.
// R9: revert GEMM to R7 (BK=64 dbuf, one barrier/iter — R8 proved BK=32 dbuf
//     regresses: occupancy unchanged, 2x barriers = +18 us). New: GEMM3
//     residual read from bf16 xb (-48 MB HBM); single fused prep kernel
//     (cast + 3 transposes, one launch).
// ---------------------------------------------------------------------------

typedef __bf16 bf16x8 __attribute__((ext_vector_type(8)));
typedef __bf16 bf16x4 __attribute__((ext_vector_type(4)));
typedef __bf16 bf16x2 __attribute__((ext_vector_type(2)));
typedef float  f32x4  __attribute__((ext_vector_type(4)));

typedef __attribute__((address_space(1))) void* gas_ptr;
typedef __attribute__((address_space(3))) void* las_ptr;

// wave-uniform LDS base; each lane deposits 16 B at base + lane*16
__device__ __forceinline__ void load_lds16(const void* g, void* l) {
    __builtin_amdgcn_global_load_lds((gas_ptr)g, (las_ptr)l, 16, 0, 0);
}

// ---------------------------------------------------------------------------
// Fused prep: block ranges do (a) x->bf16 cast, (b) W_omega^T, (c) W1^T,
// (d) W2^T. One launch instead of four.
//   blocks [0, 8192)           : cast, 256 thr x float4
//   blocks [8192, 8448)        : W_omega (512x512) transpose, 16x16 tiles
//   blocks [8448, 10496)       : W1 (2048x1024) transpose, 32x64 tiles
//   blocks [10496, 11008)      : W2 (1024x512) transpose, 16x32 tiles
// ---------------------------------------------------------------------------
__device__ __forceinline__ void transpose_tile(const float* __restrict__ in,
                                               __bf16* __restrict__ out,
                                               int K, int N, int bx, int by,
                                               float (*tile)[33])
{
    const int tid = threadIdx.x;
    const int tx = tid & 31, ty = tid >> 5;       // (32, 8)
    const int n0 = bx * 32, k0 = by * 32;
    #pragma unroll
    for (int i = 0; i < 32; i += 8)
        tile[ty + i][tx] = in[(size_t)(k0 + ty + i) * N + n0 + tx];
    __syncthreads();
    #pragma unroll
    for (int i = 0; i < 32; i += 8)
        out[(size_t)(n0 + ty + i) * K + k0 + tx] = (__bf16)tile[tx][ty + i];
}

__global__ __launch_bounds__(256)
void prep_kernel(const float* __restrict__ x, __bf16* __restrict__ xb,
                 const float* __restrict__ W_omega, __bf16* __restrict__ womT,
                 const float* __restrict__ W1, __bf16* __restrict__ w1T,
                 const float* __restrict__ W2, __bf16* __restrict__ w2T)
{
    __shared__ float tile[32][33];
    const int bid = blockIdx.x;
    if (bid < 8192) {
        int i = bid * 256 + threadIdx.x;          // 2097152 float4's
        float4 v = ((const float4*)x)[i];
        bf16x4 o = { (__bf16)v.x, (__bf16)v.y, (__bf16)v.z, (__bf16)v.w };
        ((bf16x4*)xb)[i] = o;
    } else if (bid < 8448) {
        int t = bid - 8192;                       // 16 x 16
        transpose_tile(W_omega, womT, 512, 512, t & 15, t >> 4, tile);
    } else if (bid < 10496) {
        int t = bid - 8448;                       // 32 x 64
        transpose_tile(W1, w1T, 2048, 1024, t & 31, t >> 5, tile);
    } else {
        int t = bid - 10496;                      // 16 x 32
        transpose_tile(W2, w2T, 1024, 512, t & 15, t >> 4, tile);
    }
}

// ---------------------------------------------------------------------------
// bf16 MFMA GEMM (R7): C[m][n] = sum_k A[m][k] * Bt[n][k].
// 128x128 block tile, 4 waves each 64x64 (4x4 of 16x16x32 MFMA), BK=64.
// DOUBLE-BUFFERED LDS (2 x 16 KB per operand = 64 KB): one barrier per
// K-iter; prefetch of tile i+1 issued right after the barrier so the
// vmcnt(0) drain at the NEXT barrier covers loads aged a full MFMA phase.
//
// LDS rows: 128 B (64 elems), chunk c of row r at position c ^ (r&7).
//   Staging: lane l -> row (l>>3), global chunk (l&7)^((l>>3)&7); 8-lane
//   group = one permuted 128-B segment (coalesced).
//   Fragment read (k-half h): lane l reads row +i*16+(l&15), chunk
//   (4h+(l>>4)) ^ (l&7): all 32 banks hit exactly 2x -> conflict-free.
// Tile swizzle: xcd = bid&7; same-XCD blocks share tile_m -> A-strip L2 hit.
//
// MODE 0: +bias, store bf16            (omega)
// MODE 1: +bias, exact gelu, store bf16 (h)
// MODE 2: +bias, +bf16 resid, store fp32 (final out)
// ---------------------------------------------------------------------------
template<int MODE>
__global__ __launch_bounds__(256)
void gemm_kernel(const __bf16* __restrict__ A, const __bf16* __restrict__ Bt,
                 const float* __restrict__ bias, const __bf16* __restrict__ resid,
                 void* __restrict__ out, int M, int N, int K)
{
    __shared__ __bf16 As[2][128 * 64];
    __shared__ __bf16 Bs[2][128 * 64];

    const int tid     = threadIdx.x;
    const int tiles_n = N >> 7;                 // 4 or 8 (power of 2)
    const int ln_tn   = __ffs(tiles_n) - 1;
    const int per_m   = (M >> 7) >> 3;          // 128-row tiles per XCD

    const int xcd = blockIdx.x & 7;
    const int j   = blockIdx.x >> 3;
    const int tile_m = (xcd * per_m + (j >> ln_tn)) << 7;
    const int tile_n = (j & (tiles_n - 1)) << 7;

    const int wave = tid >> 6;
    const int lane = tid & 63;

    // staging map: lane l -> row (l>>3), chunk (l&7)^((l>>3)&7)
    const int srow = lane >> 3;                       // 0..7
    const int scol = ((lane & 7) ^ srow) << 3;        // elem offset in row

    const __bf16* Ags = A  + (size_t)(tile_m + wave * 32 + srow) * K + scol;
    const __bf16* Bgs = Bt + (size_t)(tile_n + wave * 32 + srow) * K + scol;

    const int m0 = (wave >> 1) << 6;
    const int n0 = (wave & 1) << 6;
    const int lr = lane & 15;
    const int q  = lane >> 4;
    const int l7 = lane & 7;
    const int fc0 = ((0 + q) ^ l7) << 3;   // swizzled elem offset, k-half 0
    const int fc1 = ((4 + q) ^ l7) << 3;   // swizzled elem offset, k-half 1

    f32x4 acc[4][4];
    #pragma unroll
    for (int i = 0; i < 4; ++i)
        #pragma unroll
        for (int jj = 0; jj < 4; ++jj)
            acc[i][jj] = (f32x4){0.f, 0.f, 0.f, 0.f};

    const int nIter = K >> 6;

    // prologue: stage tile 0 into buffer 0
    #pragma unroll
    for (int c = 0; c < 4; ++c) {
        load_lds16(Ags + (size_t)(c * 8) * K, &As[0][(wave * 32 + c * 8) * 64]);
        load_lds16(Bgs + (size_t)(c * 8) * K, &Bs[0][(wave * 32 + c * 8) * 64]);
    }

    for (int it = 0; it < nIter; ++it) {
        const int cur = it & 1;
        __syncthreads();   // drains prefetch issued last iter (aged thru MFMA)
        if (it + 1 < nIter) {
            const int nk = (it + 1) << 6;
            #pragma unroll
            for (int c = 0; c < 4; ++c) {
                load_lds16(Ags + nk + (size_t)(c * 8) * K, &As[cur ^ 1][(wave * 32 + c * 8) * 64]);
                load_lds16(Bgs + nk + (size_t)(c * 8) * K, &Bs[cur ^ 1][(wave * 32 + c * 8) * 64]);
            }
        }

        const __bf16* as = As[cur];
        const __bf16* bs = Bs[cur];
        // k-half 0
        {
            bf16x8 af[4], bq[4];
            #pragma unroll
            for (int i = 0; i < 4; ++i)
                af[i] = *(const bf16x8*)&as[(m0 + i * 16 + lr) * 64 + fc0];
            #pragma unroll
            for (int jj = 0; jj < 4; ++jj)
                bq[jj] = *(const bf16x8*)&bs[(n0 + jj * 16 + lr) * 64 + fc0];
            #pragma unroll
            for (int i = 0; i < 4; ++i)
                #pragma unroll
                for (int jj = 0; jj < 4; ++jj)
                    acc[i][jj] = __builtin_amdgcn_mfma_f32_16x16x32_bf16(af[i], bq[jj], acc[i][jj], 0, 0, 0);
        }
        // k-half 1
        {
            bf16x8 af[4], bq[4];
            #pragma unroll
            for (int i = 0; i < 4; ++i)
                af[i] = *(const bf16x8*)&as[(m0 + i * 16 + lr) * 64 + fc1];
            #pragma unroll
            for (int jj = 0; jj < 4; ++jj)
                bq[jj] = *(const bf16x8*)&bs[(n0 + jj * 16 + lr) * 64 + fc1];
            #pragma unroll
            for (int i = 0; i < 4; ++i)
                #pragma unroll
                for (int jj = 0; jj < 4; ++jj)
                    acc[i][jj] = __builtin_amdgcn_mfma_f32_16x16x32_bf16(af[i], bq[jj], acc[i][jj], 0, 0, 0);
        }
    }

    // epilogue — C/D layout: col = lane&15, row = (lane>>4)*4 + reg  [m89/m91]
    const int orow0 = tile_m + m0 + (q << 2);
    const int ocol0 = tile_n + n0 + lr;
    #pragma unroll
    for (int i = 0; i < 4; ++i) {
        #pragma unroll
        for (int jj = 0; jj < 4; ++jj) {
            const int col = ocol0 + jj * 16;
            const float bv = bias[col];
            #pragma unroll
            for (int r = 0; r < 4; ++r) {
                const int row = orow0 + i * 16 + r;
                float v = acc[i][jj][r] + bv;
                size_t idx = (size_t)row * N + col;
                if (MODE == 0) {
                    ((__bf16*)out)[idx] = (__bf16)v;
                } else if (MODE == 1) {
                    float g = 0.5f * v * (1.0f + erff(v * 0.70710678118654752f));
                    ((__bf16*)out)[idx] = (__bf16)g;
                } else {
                    ((float*)out)[idx] = v + (float)resid[idx];
                }
            }
        }
    }
}

// ---------------------------------------------------------------------------
// Per-chunk phase cumsum + rotation + running means + LayerNorm.
// One block per (b, chunk): 512 threads (8 waves), one d per thread; bf16
// inputs (xb, omega), f32 math. Double-buffered reduction slots, prefetch.
// ---------------------------------------------------------------------------
__global__ __launch_bounds__(512)
void scan_ln_kernel(const __bf16* __restrict__ xb, const __bf16* __restrict__ omega,
                    const float* __restrict__ log_scale,
                    const float* __restrict__ gamma, const float* __restrict__ beta,
                    __bf16* __restrict__ ctx)
{
    const int chunk = blockIdx.x;        // 0..255  (b*64 + n)
    const int d     = threadIdx.x;       // 0..511
    const int lane  = d & 63, wv = d >> 6;   // 8 waves
    const size_t base = (size_t)chunk * 64 * 512;

    const float scale = expf(log_scale[d]);
    const float g0 = gamma[d], g1 = gamma[512 + d], g2 = gamma[1024 + d], g3 = gamma[1536 + d];
    const float e0 = beta[d],  e1 = beta[512 + d],  e2 = beta[1024 + d],  e3 = beta[1536 + d];

    float phi = 0.f, scr = 0.f, sci = 0.f;
    __shared__ float red[2][16];         // [slot][8 sums | 8 sumsq]

    float om_n = (float)omega[base + d];
    float xv_n = (float)xb[base + d];

    for (int c = 0; c < 64; ++c) {
        const float om = om_n;
        const float xv = xv_n;
        if (c < 63) {
            om_n = (float)omega[base + (size_t)(c + 1) * 512 + d];
            xv_n = (float)xb[base + (size_t)(c + 1) * 512 + d];
        }
        phi += om * scale * rsqrtf((float)(c + 1));
        float sp, cp;
        __sincosf(phi, &sp, &cp);
        const float cr = xv * cp, ci = xv * sp;
        scr += cr; sci += ci;
        const float inv = 1.0f / (float)(c + 1);
        const float mr = scr * inv, mi = sci * inv;
        const float rr = mr * cp + mi * sp;
        const float ri = mi * cp - mr * sp;

        float s  = cr + ci + rr + ri;
        float s2 = cr * cr + ci * ci + rr * rr + ri * ri;
        #pragma unroll
        for (int o = 32; o > 0; o >>= 1) {
            s  += __shfl_down(s, o);
            s2 += __shfl_down(s2, o);
        }
        if (lane == 0) { red[c & 1][wv] = s; red[c & 1][8 + wv] = s2; }
        __syncthreads();
        float S = 0.f, S2 = 0.f;
        #pragma unroll
        for (int i = 0; i < 8; ++i) { S += red[c & 1][i]; S2 += red[c & 1][8 + i]; }
        const float mu   = S * (1.0f / 2048.0f);
        const float var  = S2 * (1.0f / 2048.0f) - mu * mu;
        const float rstd = rsqrtf(var + 1e-5f);

        const size_t ob = ((size_t)chunk * 64 + c) * 2048;
        ctx[ob + d]        = (__bf16)(((cr - mu) * rstd) * g0 + e0);
        ctx[ob + 512 + d]  = (__bf16)(((ci - mu) * rstd) * g1 + e1);
        ctx[ob + 1024 + d] = (__bf16)(((rr - mu) * rstd) * g2 + e2);
        ctx[ob + 1536 + d] = (__bf16)(((ri - mu) * rstd) * g3 + e3);
    }
}

// ---------------------------------------------------------------------------
// Workspace layout (bytes):
//   xb    @ 0          : 16,777,216  (16384x512 bf16)
//   womT  @ 16777216   : 524,288     (512x512 bf16, transposed)
//   w1T   @ 17301504   : 4,194,304   (1024x2048 bf16, transposed)
//   w2T   @ 21495808   : 1,048,576   (512x1024 bf16, transposed)
//   omega @ 22544384   : 16,777,216  (16384x512 bf16) — region reused as h
//   h     @ 22544384   : 33,554,432  (16384x1024 bf16)
//   ctx   @ 56098816   : 67,108,864  (16384x2048 bf16)
// ---------------------------------------------------------------------------
extern "C" void kernel_launch(void* const* d_in, const int* in_sizes, int n_in,
                              void* d_out, int out_size, void* d_ws, size_t ws_size,
                              hipStream_t stream)
{
    const float* x         = (const float*)d_in[0];
    const float* W_omega   = (const float*)d_in[1];
    const float* b_omega   = (const float*)d_in[2];
    const float* log_scale = (const float*)d_in[3];
    const float* ln_gamma  = (const float*)d_in[4];
    const float* ln_beta   = (const float*)d_in[5];
    const float* W1        = (const float*)d_in[6];
    const float* b1        = (const float*)d_in[7];
    const float* W2        = (const float*)d_in[8];
    const float* b2        = (const float*)d_in[9];
    float* out = (float*)d_out;

    char* ws = (char*)d_ws;
    __bf16* xb    = (__bf16*)(ws);
    __bf16* womT  = (__bf16*)(ws + 16777216);
    __bf16* w1T   = (__bf16*)(ws + 17301504);
    __bf16* w2T   = (__bf16*)(ws + 21495808);
    __bf16* omega = (__bf16*)(ws + 22544384);
    __bf16* hbuf  = (__bf16*)(ws + 22544384);   // reuses omega region
    __bf16* ctx   = (__bf16*)(ws + 56098816);

    // 1. fused cast + weight transposes (one launch)
    prep_kernel<<<11008, 256, 0, stream>>>(x, xb, W_omega, womT, W1, w1T, W2, w2T);

    // 2. omega = x @ W_omega + b_omega   (bf16 out)
    gemm_kernel<0><<<512, 256, 0, stream>>>(xb, womT, b_omega, nullptr, omega, 16384, 512, 512);

    // 3. chunk scan + LayerNorm -> ctx (bf16, 16384x2048)
    scan_ln_kernel<<<256, 512, 0, stream>>>(xb, omega, log_scale, ln_gamma, ln_beta, ctx);

    // 4. h = gelu(ctx @ W1 + b1)  (bf16 out)
    gemm_kernel<1><<<1024, 256, 0, stream>>>(ctx, w1T, b1, nullptr, hbuf, 16384, 1024, 2048);

    // 5. out = x + h @ W2 + b2    (fp32 out, bf16 residual)
    gemm_kernel<2><<<512, 256, 0, stream>>>(hbuf, w2T, b2, xb, out, 16384, 512, 1024);
}